// Round 1
// baseline (110.238 us; speedup 1.0000x reference)
//
#include <hip/hip_runtime.h>
#include <hip/hip_bf16.h>
#include <math.h>

// Problem constants (B=512, D=768, H=256)
#define B 512
#define D 768
#define H 256
#define NN 128          // n = B/4
#define MM 256          // m = B/2
#define P_PAIRS 57280   // sum_{i=0}^{127} (511 - i)
#define NPBLK_P 448     // pair-tiles of 128 (last one half-padded)

typedef _Float16 f16x8 __attribute__((ext_vector_type(8)));
typedef float f32x4 __attribute__((ext_vector_type(4)));

// MFMA 16x16x32 f16:
//   A[m = lane&15][k = (lane>>4)*8 + e]; B from row-major [n][k] same pattern
//   C/D: col = lane&15, row = (lane>>4)*4 + reg
// Frag-tile layout: flat = ((g*S + s)*64 + lane)*8 + e  <=>  M[16g + (lane&15)][32s + (lane>>4)*8 + e]
//
// Structure note (R12 post-mortem, prev session): 4-kernel chain at ~101 µs beat
// cooperative mega-kernel (launch fails), device-fence fused variants (+10 µs).
// This round: chain is stage-latency bound (compute floor ~8 µs, HBM floor ~2 µs,
// measured 99 µs) -> fold k_uv into k_prep by building uv fragments directly from
// fp32 emb/W1 (inline norm+cvt). 4 kernels -> 3; W1H staging deleted.

__device__ __forceinline__ f16x8 cvt8s(float4 a, float4 b, float sc) {
    f16x8 o;
    o[0] = (_Float16)(a.x * sc); o[1] = (_Float16)(a.y * sc);
    o[2] = (_Float16)(a.z * sc); o[3] = (_Float16)(a.w * sc);
    o[4] = (_Float16)(b.x * sc); o[5] = (_Float16)(b.y * sc);
    o[6] = (_Float16)(b.z * sc); o[7] = (_Float16)(b.w * sc);
    return o;
}

__device__ __forceinline__ f16x8 cvt8(float4 a, float4 b) {
    f16x8 o;
    o[0] = (_Float16)a.x; o[1] = (_Float16)a.y;
    o[2] = (_Float16)a.z; o[3] = (_Float16)a.w;
    o[4] = (_Float16)b.x; o[5] = (_Float16)b.y;
    o[6] = (_Float16)b.z; o[7] = (_Float16)b.w;
    return o;
}

// ---------------- K_A: prep + uv, 224 blocks x 256 threads ----------------
// blocks [0,64):    z rows [8bx, 8bx+8) -> norms + zH frag-tiles (for sim)
// blocks [64,96):   W2H frag-tiles (group (bx-64)>>1, s-half (bx-64)&1)
// blocks [96,224):  uv GEMM direct from fp32 emb/W1 (4 wave-tiles per block)
__global__ __launch_bounds__(256) void k_prep_uv(const float* __restrict__ emb,
                                                 const float* __restrict__ W1,
                                                 const float* __restrict__ W2,
                                                 const float* __restrict__ b1,
                                                 _Float16* __restrict__ zH,
                                                 _Float16* __restrict__ W2H,
                                                 _Float16* __restrict__ Up,
                                                 _Float16* __restrict__ Vv) {
    __shared__ float invs[16];
    int bx = blockIdx.x;
    int tid = threadIdx.x;
    int w = tid >> 6, lane = tid & 63;

    if (bx < 64) {
        int g8 = bx;                    // 8-row block
        int grp = g8 >> 1;              // frag group 0..31
        int h = g8 & 1;                 // row half within group
        // phase 1: norms (wave w -> rows 2w, 2w+1)
        #pragma unroll
        for (int rr = 0; rr < 2; rr++) {
            int r8 = 2 * w + rr;        // 0..7
            const float* rp = emb + (8 * g8 + r8) * D;
            float ss = 0.f;
            #pragma unroll
            for (int it = 0; it < 12; it++) {
                float v = rp[lane + 64 * it];
                ss += v * v;
            }
            #pragma unroll
            for (int m = 1; m <= 32; m <<= 1) ss += __shfl_xor(ss, m);
            if (lane == 0) invs[r8] = 1.0f / fmaxf(sqrtf(ss), 1e-12f);
        }
        __syncthreads();
        // phase 2: 768 chunks = 24 s x 4 q x 8 r8
        #pragma unroll
        for (int it = 0; it < 3; it++) {
            int chunk = it * 256 + tid;
            int s = chunk >> 5;
            int x = chunk & 31;
            int q = x >> 3, r8 = x & 7;
            int r = h * 8 + r8;
            const float* src = emb + (8 * g8 + r8) * D + 32 * s + 8 * q;
            float inv = invs[r8];
            float4 a = *(const float4*)src;
            float4 bb = *(const float4*)(src + 4);
            *(f16x8*)(zH + ((grp * 24 + s) * 64 + q * 16 + r) * 8) = cvt8s(a, bb, inv);
        }
    } else if (bx < 96) {
        // W2H: group g, s-half sh; 256 chunks = 4 s x 64 lc
        int g = (bx - 64) >> 1;
        int sh = (bx - 64) & 1;
        int s = sh * 4 + (tid >> 6);
        int lc = tid & 63;
        int q = lc >> 4, r = lc & 15;
        const float* src = W2 + (16 * g + r) * H + 32 * s + 8 * q;
        float4 a = *(const float4*)src;
        float4 bb = *(const float4*)(src + 4);
        *(f16x8*)(W2H + ((g * 8 + s) * 64 + lc) * 8) = cvt8(a, bb);
    } else {
        // ---- uv GEMM: gid = (bx-96)*4 + w in [0,512); gm shared by block ----
        int gblk = bx - 96;                  // 0..127
        int gm = gblk >> 2;                  // 0..31 (same for all 4 waves)
        int gnp = (gblk & 3) * 4 + w;        // 0..15

        // norms for rows gm*16 .. gm*16+15 (wave w -> rows 4w..4w+3)
        #pragma unroll
        for (int rr = 0; rr < 4; rr++) {
            int r16 = 4 * w + rr;
            const float* rp = emb + (gm * 16 + r16) * D;
            float ss = 0.f;
            #pragma unroll
            for (int it = 0; it < 12; it++) {
                float v = rp[lane + 64 * it];
                ss += v * v;
            }
            #pragma unroll
            for (int m = 1; m <= 32; m <<= 1) ss += __shfl_xor(ss, m);
            if (lane == 0) invs[r16] = 1.0f / fmaxf(sqrtf(ss), 1e-12f);
        }
        __syncthreads();

        int r = lane & 15, q = lane >> 4;
        float inv = invs[r];
        const float* arow = emb + (gm * 16 + r) * D + 8 * q;
        const float* brow[2];
        #pragma unroll
        for (int nt = 0; nt < 2; nt++) {
            int n = (gnp * 2 + nt) * 16 + r;
            brow[nt] = W1 + (n & 255) * (2 * D) + (n >> 8) * D + 8 * q;
        }

        f32x4 acc[2] = {};
        #pragma unroll 4
        for (int s = 0; s < 24; s++) {
            float4 a0 = *(const float4*)(arow + 32 * s);
            float4 a1 = *(const float4*)(arow + 32 * s + 4);
            f16x8 a = cvt8s(a0, a1, inv);
            #pragma unroll
            for (int nt = 0; nt < 2; nt++) {
                float4 b0 = *(const float4*)(brow[nt] + 32 * s);
                float4 b1v = *(const float4*)(brow[nt] + 32 * s + 4);
                f16x8 bb = cvt8(b0, b1v);
                acc[nt] = __builtin_amdgcn_mfma_f32_16x16x32_f16(a, bb, acc[nt], 0, 0, 0);
            }
        }
        #pragma unroll
        for (int nt = 0; nt < 2; nt++) {
            int n = (gnp * 2 + nt) * 16 + r;
            float bias = (n < H) ? b1[n] : 0.f;
            #pragma unroll
            for (int rr = 0; rr < 4; rr++) {
                int m = gm * 16 + 4 * q + rr;
                float C = acc[nt][rr] + bias;
                if (n < H) Up[m * H + n] = (_Float16)C;
                else       Vv[m * H + (n - H)] = (_Float16)C;
            }
        }
    }
}

// ---------------- K2: pair MLP (448 x 128-pair tiles) + sim rides in blocks [448,464) ----------------
__global__ __launch_bounds__(256, 2) void k_pairs(const _Float16* __restrict__ Up,
                                                  const _Float16* __restrict__ Vv,
                                                  const _Float16* __restrict__ W2H,
                                                  const _Float16* __restrict__ zH,
                                                  const float* __restrict__ b2,
                                                  const float* __restrict__ W3,
                                                  const float* __restrict__ b3,
                                                  float* __restrict__ bcepart,
                                                  float* __restrict__ esp,   // [8][128]
                                                  float* __restrict__ slp) { // [8][128]
    int tid = threadIdx.x;
    int w = tid >> 6, lane = tid & 63;
    int r = lane & 15, q = lane >> 4;
    int bx = blockIdx.x;

    if (bx >= NPBLK_P) {
        // ---- similarity stats: wave tile t = (bx-448)*4+w ----
        int t = (bx - NPBLK_P) * 4 + w;      // 0..63
        int gm = t >> 3;                     // rows < 128
        int slot = t & 7;
        int gn0 = slot * 4;
        f32x4 acc[4] = {};
        #pragma unroll 4
        for (int s = 0; s < 24; s++) {
            f16x8 a = *(const f16x8*)(zH + ((gm * 24 + s) * 64 + lane) * 8);
            #pragma unroll
            for (int nt = 0; nt < 4; nt++) {
                f16x8 bb = *(const f16x8*)(zH + (((gn0 + nt) * 24 + s) * 64 + lane) * 8);
                acc[nt] = __builtin_amdgcn_mfma_f32_16x16x32_f16(a, bb, acc[nt], 0, 0, 0);
            }
        }
        #pragma unroll
        for (int rr = 0; rr < 4; rr++) {
            int irow = gm * 16 + q * 4 + rr;
            float es = 0.f, sl = 0.f;
            #pragma unroll
            for (int nt = 0; nt < 4; nt++) {
                int kcol = (gn0 + nt) * 16 + r;
                float C = acc[nt][rr];
                if (kcol != irow) es += expf(2.f * C);
                if (kcol > irow && kcol < NN) sl += 2.f * C;
            }
            #pragma unroll
            for (int m = 1; m <= 8; m <<= 1) {
                es += __shfl_xor(es, m);
                sl += __shfl_xor(sl, m);
            }
            if (r == 0) {
                esp[slot * NN + irow] = es;
                slp[slot * NN + irow] = sl;
            }
        }
        return;
    }

    // ---- pair blocks ----
    __shared__ _Float16 h1[128][264];    // 66 KB
    __shared__ float redbuf[4][128];
    __shared__ float red2[2];

    int p0 = bx * 128;

    // stage h1 = relu(U'[i] + V[j]) f16; (i,j) computed inline per unit (no barrier)
    #pragma unroll
    for (int uu = 0; uu < 2; uu++) {
        int u = uu * 256 + tid;              // 0..511
        int row = u >> 2, cq = u & 3;
        int p = p0 + row;
        if (p >= P_PAIRS) p = P_PAIRS - 1;   // pad rows duplicate last pair (masked later)
        float disc = 1046529.f - 8.f * (float)p;   // 1023^2 - 8p, exact in fp32
        int i = (int)((1023.f - sqrtf(disc)) * 0.5f);
        if (i < 0) i = 0;
        if (i > NN - 1) i = NN - 1;
        while (i > 0 && i * (1023 - i) / 2 > p) i--;
        while ((i + 1) * (1022 - i) / 2 <= p) i++;
        int j = i + 1 + (p - i * (1023 - i) / 2);

        const _Float16* up = Up + i * H + 64 * cq;
        const _Float16* vp = Vv + j * H + 64 * cq;
        #pragma unroll
        for (int c8 = 0; c8 < 8; c8++) {
            f16x8 u8 = *(const f16x8*)(up + 8 * c8);
            f16x8 v8 = *(const f16x8*)(vp + 8 * c8);
            f16x8 zero = {};
            f16x8 hv = __builtin_elementwise_max(u8 + v8, zero);
            *(f16x8*)&h1[row][64 * cq + 8 * c8] = hv;
        }
    }
    __syncthreads();

    // MFMA: C[128 pairs][64 cols per wave] = h1 @ W2^T
    f32x4 acc[8][4] = {};                    // [mt][nt]
    #pragma unroll
    for (int s = 0; s < 8; s++) {
        f16x8 bb[4];
        #pragma unroll
        for (int nt = 0; nt < 4; nt++)
            bb[nt] = *(const f16x8*)(W2H + (((4 * w + nt) * 8 + s) * 64 + lane) * 8);
        #pragma unroll
        for (int mt = 0; mt < 8; mt++) {
            f16x8 a = *(const f16x8*)&h1[16 * mt + r][32 * s + 8 * q];
            #pragma unroll
            for (int nt = 0; nt < 4; nt++)
                acc[mt][nt] = __builtin_amdgcn_mfma_f32_16x16x32_f16(a, bb[nt], acc[mt][nt], 0, 0, 0);
        }
    }

    // epilogue: h2 = relu(C + b2), partial logit = sum_n h2*W3
    float b2v[4], w3v[4];
    #pragma unroll
    for (int nt = 0; nt < 4; nt++) {
        int n = 64 * w + 16 * nt + r;
        b2v[nt] = b2[n];
        w3v[nt] = W3[n];
    }
    #pragma unroll
    for (int mt = 0; mt < 8; mt++) {
        float part[4] = {0.f, 0.f, 0.f, 0.f};
        #pragma unroll
        for (int nt = 0; nt < 4; nt++)
            #pragma unroll
            for (int rr = 0; rr < 4; rr++) {
                float h2 = fmaxf(acc[mt][nt][rr] + b2v[nt], 0.f);
                part[rr] += h2 * w3v[nt];
            }
        #pragma unroll
        for (int rr = 0; rr < 4; rr++) {
            float v = part[rr];
            #pragma unroll
            for (int m = 1; m <= 8; m <<= 1) v += __shfl_xor(v, m);
            if (r == 0) redbuf[w][16 * mt + 4 * q + rr] = v;
        }
    }
    __syncthreads();

    if (tid < 128) {
        int p = p0 + tid;
        float lsum = 0.f;
        if (p < P_PAIRS) {
            // recompute j for label
            float disc = 1046529.f - 8.f * (float)p;
            int i = (int)((1023.f - sqrtf(disc)) * 0.5f);
            if (i < 0) i = 0;
            if (i > NN - 1) i = NN - 1;
            while (i > 0 && i * (1023 - i) / 2 > p) i--;
            while ((i + 1) * (1022 - i) / 2 <= p) i++;
            int j = i + 1 + (p - i * (1023 - i) / 2);

            float logit = redbuf[0][tid] + redbuf[1][tid] +
                          redbuf[2][tid] + redbuf[3][tid] + b3[0];
            float label = (j < MM) ? 1.f : 0.f;
            lsum = fmaxf(logit, 0.f) - logit * label + log1pf(expf(-fabsf(logit)));
        }
        #pragma unroll
        for (int off = 32; off > 0; off >>= 1) lsum += __shfl_down(lsum, off);
        if ((tid & 63) == 0) red2[tid >> 6] = lsum;
    }
    __syncthreads();
    if (tid == 0) bcepart[bx] = red2[0] + red2[1];   // plain store, no atomic/fence
}

// ---------------- K3: final combine ----------------
__global__ __launch_bounds__(256) void k_final(const float* __restrict__ esp,
                                               const float* __restrict__ slp,
                                               const float* __restrict__ bcepart,
                                               float* __restrict__ out) {
    __shared__ float red[256];
    int t = threadIdx.x;

    float s = 0.f;
    for (int p = t; p < NPBLK_P; p += 256) s += bcepart[p];
    red[t] = s;
    __syncthreads();
    for (int st = 128; st > 0; st >>= 1) {
        if (t < st) red[t] += red[t + st];
        __syncthreads();
    }
    float bce_total = red[0];
    __syncthreads();

    float v = 0.f;
    if (t < NN) {
        float es = 0.f, sl = 0.f;
        #pragma unroll
        for (int s8 = 0; s8 < 8; s8++) {
            es += esp[s8 * NN + t];
            sl += slp[s8 * NN + t];
        }
        v = (float)(NN - 1 - t) * logf(es) - sl;
    }
    red[t] = v;
    __syncthreads();
    for (int st = 128; st > 0; st >>= 1) {
        if (t < st) red[t] += red[t + st];
        __syncthreads();
    }
    if (t == 0) {
        float closs = (-2.0f * (float)(NN - 1) / (float)NN) * red[0];
        out[0] = closs + bce_total / (float)P_PAIRS;
    }
}

extern "C" void kernel_launch(void* const* d_in, const int* in_sizes, int n_in,
                              void* d_out, int out_size, void* d_ws, size_t ws_size,
                              hipStream_t stream) {
    const float* emb = (const float*)d_in[0];
    const float* W1  = (const float*)d_in[1];
    const float* b1  = (const float*)d_in[2];
    const float* W2  = (const float*)d_in[3];
    const float* b2  = (const float*)d_in[4];
    const float* W3  = (const float*)d_in[5];
    const float* b3  = (const float*)d_in[6];
    float* out = (float*)d_out;

    float* ws = (float*)d_ws;
    float* esp     = ws;                         // 8*128
    float* slp     = ws + 1024;                  // 8*128
    float* bcepart = ws + 2048;                  // 448
    _Float16* zH  = (_Float16*)(ws + 3072);      // 512*768 frag-tiled
    _Float16* W2H = zH + B * D;                  // 256*256 frag-tiled
    _Float16* Up  = W2H + H * H;                 // 512*256 row-major
    _Float16* Vv  = Up + B * H;                  // 512*256 row-major

    k_prep_uv<<<224, 256, 0, stream>>>(emb, W1, W2, b1, zH, W2H, Up, Vv);
    k_pairs<<<NPBLK_P + 16, 256, 0, stream>>>(Up, Vv, W2H, zH, b2, W3, b3,
                                              bcepart, esp, slp);
    k_final<<<1, 256, 0, stream>>>(esp, slp, bcepart, out);
}

// Round 2
// 105.108 us; speedup vs baseline: 1.0488x; 1.0488x over previous
//
#include <hip/hip_runtime.h>
#include <hip/hip_bf16.h>
#include <math.h>

// Problem constants (B=512, D=768, H=256)
#define B 512
#define D 768
#define H 256
#define NN 128          // n = B/4
#define MM 256          // m = B/2
#define P_PAIRS 57280   // sum_{i=0}^{127} (511 - i)
#define NPBLK_P 448     // pair-tiles of 128 (last one half-padded)

typedef _Float16 f16x8 __attribute__((ext_vector_type(8)));
typedef float f32x4 __attribute__((ext_vector_type(4)));

// MFMA 16x16x32 f16:
//   A[m = lane&15][k = (lane>>4)*8 + e]; B from row-major [n][k] same pattern
//   C/D: col = lane&15, row = (lane>>4)*4 + reg
// Frag-tile layout: flat = ((g*S + s)*64 + lane)*8 + e  <=>  M[16g + (lane&15)][32s + (lane>>4)*8 + e]
//
// Structure journal:
//  R0 (prev session): 4-kernel chain k_prep -> k_uv -> k_pairs(+sim) -> k_final, 99.2 us.
//  R1: fused uv into prep rebuilding BOTH operands fp32->f16 per wave at 1 wave/SIMD:
//      110.2 us (+11). Lesson: per-wave fp32 rebuild of A is the regression, not fusion itself.
//  R2 (this): 3 kernels. uv blocks stage the z-tile in LDS ONCE per block (conflict-free
//      frag layout), publish zH from there (prep z-blocks deleted), B read fp32+inline cvt
//      (W1H staging deleted). k_pairs / k_final byte-identical to R0.

__device__ __forceinline__ f16x8 cvt8s(float4 a, float4 b, float sc) {
    f16x8 o;
    o[0] = (_Float16)(a.x * sc); o[1] = (_Float16)(a.y * sc);
    o[2] = (_Float16)(a.z * sc); o[3] = (_Float16)(a.w * sc);
    o[4] = (_Float16)(b.x * sc); o[5] = (_Float16)(b.y * sc);
    o[6] = (_Float16)(b.z * sc); o[7] = (_Float16)(b.w * sc);
    return o;
}

__device__ __forceinline__ f16x8 cvt8(float4 a, float4 b) {
    f16x8 o;
    o[0] = (_Float16)a.x; o[1] = (_Float16)a.y;
    o[2] = (_Float16)a.z; o[3] = (_Float16)a.w;
    o[4] = (_Float16)b.x; o[5] = (_Float16)b.y;
    o[6] = (_Float16)b.z; o[7] = (_Float16)b.w;
    return o;
}

// ---------------- K1: uv GEMM (blocks 0..127, LDS-staged A) + W2H staging (128..159) ----------------
__global__ __launch_bounds__(256) void k_uvprep(const float* __restrict__ emb,
                                                const float* __restrict__ W1,
                                                const float* __restrict__ W2,
                                                const float* __restrict__ b1,
                                                _Float16* __restrict__ zH,
                                                _Float16* __restrict__ W2H,
                                                _Float16* __restrict__ Up,
                                                _Float16* __restrict__ Vv) {
    int bx = blockIdx.x;
    int tid = threadIdx.x;
    int w = tid >> 6, lane = tid & 63;

    if (bx >= 128) {
        // ---- W2H frag-tiles: group g, s-half sh; 256 chunks = 4 s x 64 lc ----
        int g = (bx - 128) >> 1;
        int sh = (bx - 128) & 1;
        int s = sh * 4 + (tid >> 6);
        int lc = tid & 63;
        int q = lc >> 4, r = lc & 15;
        const float* src = W2 + (16 * g + r) * H + 32 * s + 8 * q;
        float4 a = *(const float4*)src;
        float4 bb = *(const float4*)(src + 4);
        *(f16x8*)(W2H + ((g * 8 + s) * 64 + lc) * 8) = cvt8(a, bb);
        return;
    }

    // ---- uv blocks: 4 blocks per 16-row group gm; wave-tile gnp = (bx&3)*4 + w ----
    __shared__ float invs[16];
    __shared__ _Float16 Az[1536 * 8];      // 24 KB: z-tile frag layout [s][l][e]

    int gm = bx >> 2;                      // 0..31
    int gq = bx & 3;

    // phase 0: norms (wave w -> rows 4w..4w+3)
    #pragma unroll
    for (int rr = 0; rr < 4; rr++) {
        int r16 = 4 * w + rr;
        const float* rp = emb + (gm * 16 + r16) * D;
        float ss = 0.f;
        #pragma unroll
        for (int it = 0; it < 12; it++) {
            float v = rp[lane + 64 * it];
            ss += v * v;
        }
        #pragma unroll
        for (int m = 1; m <= 32; m <<= 1) ss += __shfl_xor(ss, m);
        if (lane == 0) invs[r16] = 1.0f / fmaxf(sqrtf(ss), 1e-12f);
    }
    __syncthreads();

    // phase 1: stage z-tile f16 frags into LDS (contiguous 16B lanes -> conflict-free)
    #pragma unroll
    for (int k = 0; k < 6; k++) {
        int u = k * 256 + tid;             // 0..1535 = [s:24][l:64]
        int s = u >> 6, l = u & 63;
        int q = l >> 4, r = l & 15;
        const float* src = emb + (gm * 16 + r) * D + 32 * s + 8 * q;
        float inv = invs[r];
        float4 a = *(const float4*)src;
        float4 bb = *(const float4*)(src + 4);
        *(f16x8*)&Az[u * 8] = cvt8s(a, bb, inv);
    }
    __syncthreads();

    // one quarter-block per group publishes zH for the sim rider in K2
    if (gq == 0) {
        #pragma unroll
        for (int k = 0; k < 6; k++) {
            int u = k * 256 + tid;
            *(f16x8*)(zH + (gm * 1536 + u) * 8) = *(const f16x8*)&Az[u * 8];
        }
    }

    // phase 2: per-wave GEMM, A from LDS, B = W1 fp32 + inline cvt
    int gnp = gq * 4 + w;                  // 0..15
    int r = lane & 15, q = lane >> 4;
    const float* brow[2];
    #pragma unroll
    for (int nt = 0; nt < 2; nt++) {
        int n = (gnp * 2 + nt) * 16 + r;
        brow[nt] = W1 + (n & 255) * (2 * D) + (n >> 8) * D + 8 * q;
    }

    f32x4 acc[2] = {};
    #pragma unroll 4
    for (int s = 0; s < 24; s++) {
        f16x8 a = *(const f16x8*)&Az[(s * 64 + lane) * 8];
        #pragma unroll
        for (int nt = 0; nt < 2; nt++) {
            float4 b0 = *(const float4*)(brow[nt] + 32 * s);
            float4 b1v = *(const float4*)(brow[nt] + 32 * s + 4);
            acc[nt] = __builtin_amdgcn_mfma_f32_16x16x32_f16(a, cvt8(b0, b1v), acc[nt], 0, 0, 0);
        }
    }
    #pragma unroll
    for (int nt = 0; nt < 2; nt++) {
        int n = (gnp * 2 + nt) * 16 + r;
        float bias = (n < H) ? b1[n] : 0.f;
        #pragma unroll
        for (int rr = 0; rr < 4; rr++) {
            int m = gm * 16 + 4 * q + rr;
            float C = acc[nt][rr] + bias;
            if (n < H) Up[m * H + n] = (_Float16)C;
            else       Vv[m * H + (n - H)] = (_Float16)C;
        }
    }
}

// ---------------- K2: pair MLP (448 x 128-pair tiles) + sim rides in blocks [448,464) ----------------
__global__ __launch_bounds__(256, 2) void k_pairs(const _Float16* __restrict__ Up,
                                                  const _Float16* __restrict__ Vv,
                                                  const _Float16* __restrict__ W2H,
                                                  const _Float16* __restrict__ zH,
                                                  const float* __restrict__ b2,
                                                  const float* __restrict__ W3,
                                                  const float* __restrict__ b3,
                                                  float* __restrict__ bcepart,
                                                  float* __restrict__ esp,   // [8][128]
                                                  float* __restrict__ slp) { // [8][128]
    int tid = threadIdx.x;
    int w = tid >> 6, lane = tid & 63;
    int r = lane & 15, q = lane >> 4;
    int bx = blockIdx.x;

    if (bx >= NPBLK_P) {
        // ---- similarity stats: wave tile t = (bx-448)*4+w ----
        int t = (bx - NPBLK_P) * 4 + w;      // 0..63
        int gm = t >> 3;                     // rows < 128
        int slot = t & 7;
        int gn0 = slot * 4;
        f32x4 acc[4] = {};
        #pragma unroll 4
        for (int s = 0; s < 24; s++) {
            f16x8 a = *(const f16x8*)(zH + ((gm * 24 + s) * 64 + lane) * 8);
            #pragma unroll
            for (int nt = 0; nt < 4; nt++) {
                f16x8 bb = *(const f16x8*)(zH + (((gn0 + nt) * 24 + s) * 64 + lane) * 8);
                acc[nt] = __builtin_amdgcn_mfma_f32_16x16x32_f16(a, bb, acc[nt], 0, 0, 0);
            }
        }
        #pragma unroll
        for (int rr = 0; rr < 4; rr++) {
            int irow = gm * 16 + q * 4 + rr;
            float es = 0.f, sl = 0.f;
            #pragma unroll
            for (int nt = 0; nt < 4; nt++) {
                int kcol = (gn0 + nt) * 16 + r;
                float C = acc[nt][rr];
                if (kcol != irow) es += expf(2.f * C);
                if (kcol > irow && kcol < NN) sl += 2.f * C;
            }
            #pragma unroll
            for (int m = 1; m <= 8; m <<= 1) {
                es += __shfl_xor(es, m);
                sl += __shfl_xor(sl, m);
            }
            if (r == 0) {
                esp[slot * NN + irow] = es;
                slp[slot * NN + irow] = sl;
            }
        }
        return;
    }

    // ---- pair blocks ----
    __shared__ _Float16 h1[128][264];    // 66 KB
    __shared__ float redbuf[4][128];
    __shared__ float red2[2];

    int p0 = bx * 128;

    // stage h1 = relu(U'[i] + V[j]) f16; (i,j) computed inline per unit (no barrier)
    #pragma unroll
    for (int uu = 0; uu < 2; uu++) {
        int u = uu * 256 + tid;              // 0..511
        int row = u >> 2, cq = u & 3;
        int p = p0 + row;
        if (p >= P_PAIRS) p = P_PAIRS - 1;   // pad rows duplicate last pair (masked later)
        float disc = 1046529.f - 8.f * (float)p;   // 1023^2 - 8p, exact in fp32
        int i = (int)((1023.f - sqrtf(disc)) * 0.5f);
        if (i < 0) i = 0;
        if (i > NN - 1) i = NN - 1;
        while (i > 0 && i * (1023 - i) / 2 > p) i--;
        while ((i + 1) * (1022 - i) / 2 <= p) i++;
        int j = i + 1 + (p - i * (1023 - i) / 2);

        const _Float16* up = Up + i * H + 64 * cq;
        const _Float16* vp = Vv + j * H + 64 * cq;
        #pragma unroll
        for (int c8 = 0; c8 < 8; c8++) {
            f16x8 u8 = *(const f16x8*)(up + 8 * c8);
            f16x8 v8 = *(const f16x8*)(vp + 8 * c8);
            f16x8 zero = {};
            f16x8 hv = __builtin_elementwise_max(u8 + v8, zero);
            *(f16x8*)&h1[row][64 * cq + 8 * c8] = hv;
        }
    }
    __syncthreads();

    // MFMA: C[128 pairs][64 cols per wave] = h1 @ W2^T
    f32x4 acc[8][4] = {};                    // [mt][nt]
    #pragma unroll
    for (int s = 0; s < 8; s++) {
        f16x8 bb[4];
        #pragma unroll
        for (int nt = 0; nt < 4; nt++)
            bb[nt] = *(const f16x8*)(W2H + (((4 * w + nt) * 8 + s) * 64 + lane) * 8);
        #pragma unroll
        for (int mt = 0; mt < 8; mt++) {
            f16x8 a = *(const f16x8*)&h1[16 * mt + r][32 * s + 8 * q];
            #pragma unroll
            for (int nt = 0; nt < 4; nt++)
                acc[mt][nt] = __builtin_amdgcn_mfma_f32_16x16x32_f16(a, bb[nt], acc[mt][nt], 0, 0, 0);
        }
    }

    // epilogue: h2 = relu(C + b2), partial logit = sum_n h2*W3
    float b2v[4], w3v[4];
    #pragma unroll
    for (int nt = 0; nt < 4; nt++) {
        int n = 64 * w + 16 * nt + r;
        b2v[nt] = b2[n];
        w3v[nt] = W3[n];
    }
    #pragma unroll
    for (int mt = 0; mt < 8; mt++) {
        float part[4] = {0.f, 0.f, 0.f, 0.f};
        #pragma unroll
        for (int nt = 0; nt < 4; nt++)
            #pragma unroll
            for (int rr = 0; rr < 4; rr++) {
                float h2 = fmaxf(acc[mt][nt][rr] + b2v[nt], 0.f);
                part[rr] += h2 * w3v[nt];
            }
        #pragma unroll
        for (int rr = 0; rr < 4; rr++) {
            float v = part[rr];
            #pragma unroll
            for (int m = 1; m <= 8; m <<= 1) v += __shfl_xor(v, m);
            if (r == 0) redbuf[w][16 * mt + 4 * q + rr] = v;
        }
    }
    __syncthreads();

    if (tid < 128) {
        int p = p0 + tid;
        float lsum = 0.f;
        if (p < P_PAIRS) {
            // recompute j for label
            float disc = 1046529.f - 8.f * (float)p;
            int i = (int)((1023.f - sqrtf(disc)) * 0.5f);
            if (i < 0) i = 0;
            if (i > NN - 1) i = NN - 1;
            while (i > 0 && i * (1023 - i) / 2 > p) i--;
            while ((i + 1) * (1022 - i) / 2 <= p) i++;
            int j = i + 1 + (p - i * (1023 - i) / 2);

            float logit = redbuf[0][tid] + redbuf[1][tid] +
                          redbuf[2][tid] + redbuf[3][tid] + b3[0];
            float label = (j < MM) ? 1.f : 0.f;
            lsum = fmaxf(logit, 0.f) - logit * label + log1pf(expf(-fabsf(logit)));
        }
        #pragma unroll
        for (int off = 32; off > 0; off >>= 1) lsum += __shfl_down(lsum, off);
        if ((tid & 63) == 0) red2[tid >> 6] = lsum;
    }
    __syncthreads();
    if (tid == 0) bcepart[bx] = red2[0] + red2[1];   // plain store, no atomic/fence
}

// ---------------- K3: final combine ----------------
__global__ __launch_bounds__(256) void k_final(const float* __restrict__ esp,
                                               const float* __restrict__ slp,
                                               const float* __restrict__ bcepart,
                                               float* __restrict__ out) {
    __shared__ float red[256];
    int t = threadIdx.x;

    float s = 0.f;
    for (int p = t; p < NPBLK_P; p += 256) s += bcepart[p];
    red[t] = s;
    __syncthreads();
    for (int st = 128; st > 0; st >>= 1) {
        if (t < st) red[t] += red[t + st];
        __syncthreads();
    }
    float bce_total = red[0];
    __syncthreads();

    float v = 0.f;
    if (t < NN) {
        float es = 0.f, sl = 0.f;
        #pragma unroll
        for (int s8 = 0; s8 < 8; s8++) {
            es += esp[s8 * NN + t];
            sl += slp[s8 * NN + t];
        }
        v = (float)(NN - 1 - t) * logf(es) - sl;
    }
    red[t] = v;
    __syncthreads();
    for (int st = 128; st > 0; st >>= 1) {
        if (t < st) red[t] += red[t + st];
        __syncthreads();
    }
    if (t == 0) {
        float closs = (-2.0f * (float)(NN - 1) / (float)NN) * red[0];
        out[0] = closs + bce_total / (float)P_PAIRS;
    }
}

extern "C" void kernel_launch(void* const* d_in, const int* in_sizes, int n_in,
                              void* d_out, int out_size, void* d_ws, size_t ws_size,
                              hipStream_t stream) {
    const float* emb = (const float*)d_in[0];
    const float* W1  = (const float*)d_in[1];
    const float* b1  = (const float*)d_in[2];
    const float* W2  = (const float*)d_in[3];
    const float* b2  = (const float*)d_in[4];
    const float* W3  = (const float*)d_in[5];
    const float* b3  = (const float*)d_in[6];
    float* out = (float*)d_out;

    float* ws = (float*)d_ws;
    float* esp     = ws;                         // 8*128
    float* slp     = ws + 1024;                  // 8*128
    float* bcepart = ws + 2048;                  // 448
    _Float16* zH  = (_Float16*)(ws + 3072);      // 512*768 frag-tiled
    _Float16* W2H = zH + B * D;                  // 256*256 frag-tiled
    _Float16* Up  = W2H + H * H;                 // 512*256 row-major
    _Float16* Vv  = Up + B * H;                  // 512*256 row-major

    k_uvprep<<<160, 256, 0, stream>>>(emb, W1, W2, b1, zH, W2H, Up, Vv);
    k_pairs<<<NPBLK_P + 16, 256, 0, stream>>>(Up, Vv, W2H, zH, b2, W3, b3,
                                              bcepart, esp, slp);
    k_final<<<1, 256, 0, stream>>>(esp, slp, bcepart, out);
}

// Round 3
// 98.331 us; speedup vs baseline: 1.1211x; 1.0689x over previous
//
#include <hip/hip_runtime.h>
#include <hip/hip_bf16.h>
#include <math.h>

// Problem constants (B=512, D=768, H=256)
#define B 512
#define D 768
#define H 256
#define NN 128          // n = B/4
#define MM 256          // m = B/2
#define P_PAIRS 57280   // sum_{i=0}^{127} (511 - i)
#define NPBLK_P 448     // pair-tiles of 128 (last one half-padded)

typedef _Float16 f16x8 __attribute__((ext_vector_type(8)));
typedef float f32x4 __attribute__((ext_vector_type(4)));

// MFMA 16x16x32 f16:
//   A[m = lane&15][k = (lane>>4)*8 + e]; B from row-major [n][k] same pattern
//   C/D: col = lane&15, row = (lane>>4)*4 + reg
// Frag-tile layout: flat = ((g*S + s)*64 + lane)*8 + e  <=>  M[16g + (lane&15)][32s + (lane>>4)*8 + e]
//
// Structure journal:
//  R0 (prev session best): 4-kernel chain k_prep -> k_uv -> k_pairs(+sim) -> k_final, 99.2 us.
//  R1: fused uv+prep, per-wave fp32 operand rebuild: 110.2 (+11). uv exec regression.
//  R2: fused uv+prep, LDS-staged A, fp32 B: 105.1 (+5.9). Boundary removal worth ~0.
//  Model (R2 post-mortem): timed window = 2x 256MiB harness ws-poison fills (~82.5 us,
//  uncontrollable) + our ~16 us chain. Optimize the chain only; floor ~93-95 us.
//  R3 (this): revert to R0 structure exactly; j-cache in k_pairs tail; k_final single-tree.

// ---------------- K0: prep, 160 blocks ----------------
// blocks [0,64):    z rows [8bx, 8bx+8) -> norms + zH frag-tiles
// blocks [64,128):  W1H frag-tiles (group (bx-64)>>1, s-half (bx-64)&1)
// blocks [128,160): W2H frag-tiles (group (bx-128)>>1, s-half (bx-128)&1)
__global__ __launch_bounds__(256) void k_prep(const float* __restrict__ emb,
                                              const float* __restrict__ W1,
                                              const float* __restrict__ W2,
                                              _Float16* __restrict__ zH,
                                              _Float16* __restrict__ W1H,
                                              _Float16* __restrict__ W2H) {
    __shared__ float invs[8];
    int bx = blockIdx.x;
    int tid = threadIdx.x;
    int w = tid >> 6, lane = tid & 63;

    if (bx < 64) {
        int g8 = bx;                    // 8-row block
        int grp = g8 >> 1;              // frag group 0..31
        int h = g8 & 1;                 // row half within group
        // phase 1: norms (wave w -> rows 2w, 2w+1)
        #pragma unroll
        for (int rr = 0; rr < 2; rr++) {
            int r8 = 2 * w + rr;        // 0..7
            const float* rp = emb + (8 * g8 + r8) * D;
            float ss = 0.f;
            #pragma unroll
            for (int it = 0; it < 12; it++) {
                float v = rp[lane + 64 * it];
                ss += v * v;
            }
            #pragma unroll
            for (int m = 1; m <= 32; m <<= 1) ss += __shfl_xor(ss, m);
            if (lane == 0) invs[r8] = 1.0f / fmaxf(sqrtf(ss), 1e-12f);
        }
        __syncthreads();
        // phase 2: 768 chunks = 24 s x 4 q x 8 r8
        #pragma unroll
        for (int it = 0; it < 3; it++) {
            int chunk = it * 256 + tid;
            int s = chunk >> 5;
            int x = chunk & 31;
            int q = x >> 3, r8 = x & 7;
            int r = h * 8 + r8;
            const float* src = emb + (8 * g8 + r8) * D + 32 * s + 8 * q;
            float inv = invs[r8];
            float4 a = *(const float4*)src;
            float4 bb = *(const float4*)(src + 4);
            f16x8 o;
            o[0] = (_Float16)(a.x * inv); o[1] = (_Float16)(a.y * inv);
            o[2] = (_Float16)(a.z * inv); o[3] = (_Float16)(a.w * inv);
            o[4] = (_Float16)(bb.x * inv); o[5] = (_Float16)(bb.y * inv);
            o[6] = (_Float16)(bb.z * inv); o[7] = (_Float16)(bb.w * inv);
            *(f16x8*)(zH + ((grp * 24 + s) * 64 + q * 16 + r) * 8) = o;
        }
    } else if (bx < 128) {
        // W1H: row n = 16g+r reads W1[n&255][(n>>8)*768 + k]
        int g = (bx - 64) >> 1;
        int sh = (bx - 64) & 1;
        #pragma unroll
        for (int it = 0; it < 3; it++) {
            int chunk = it * 256 + tid;          // 0..767
            int s = sh * 12 + (chunk >> 6);
            int lc = chunk & 63;
            int q = lc >> 4, r = lc & 15;
            int n = 16 * g + r;
            const float* src = W1 + (n & 255) * (2 * D) + (n >> 8) * D + 32 * s + 8 * q;
            float4 a = *(const float4*)src;
            float4 bb = *(const float4*)(src + 4);
            f16x8 o;
            o[0] = (_Float16)a.x; o[1] = (_Float16)a.y; o[2] = (_Float16)a.z; o[3] = (_Float16)a.w;
            o[4] = (_Float16)bb.x; o[5] = (_Float16)bb.y; o[6] = (_Float16)bb.z; o[7] = (_Float16)bb.w;
            *(f16x8*)(W1H + ((g * 24 + s) * 64 + lc) * 8) = o;
        }
    } else {
        // W2H: group g, s-half sh; 256 chunks = 4 s x 64 lc
        int g = (bx - 128) >> 1;
        int sh = (bx - 128) & 1;
        int s = sh * 4 + (tid >> 6);
        int lc = tid & 63;
        int q = lc >> 4, r = lc & 15;
        const float* src = W2 + (16 * g + r) * H + 32 * s + 8 * q;
        float4 a = *(const float4*)src;
        float4 bb = *(const float4*)(src + 4);
        f16x8 o;
        o[0] = (_Float16)a.x; o[1] = (_Float16)a.y; o[2] = (_Float16)a.z; o[3] = (_Float16)a.w;
        o[4] = (_Float16)bb.x; o[5] = (_Float16)bb.y; o[6] = (_Float16)bb.z; o[7] = (_Float16)bb.w;
        *(f16x8*)(W2H + ((g * 8 + s) * 64 + lc) * 8) = o;
    }
}

// ---------------- K1: uv, 256 blocks x 128 threads (2 wave-tiles per block) ----------------
__global__ __launch_bounds__(128) void k_uv(const _Float16* __restrict__ zH,
                                            const _Float16* __restrict__ W1H,
                                            const float* __restrict__ b1,
                                            _Float16* __restrict__ Up,
                                            _Float16* __restrict__ Vv) {
    int w = threadIdx.x >> 6;
    int lane = threadIdx.x & 63;
    int r = lane & 15, q = lane >> 4;
    int gid = blockIdx.x * 2 + w;            // 0..511
    int gm = gid >> 4;                       // 0..31
    int gnp = gid & 15;                      // n-tile pair

    f32x4 acc[2] = {};
    #pragma unroll 4
    for (int s = 0; s < 24; s++) {
        f16x8 a = *(const f16x8*)(zH + ((gm * 24 + s) * 64 + lane) * 8);
        #pragma unroll
        for (int nt = 0; nt < 2; nt++) {
            f16x8 bb = *(const f16x8*)(W1H + (((gnp * 2 + nt) * 24 + s) * 64 + lane) * 8);
            acc[nt] = __builtin_amdgcn_mfma_f32_16x16x32_f16(a, bb, acc[nt], 0, 0, 0);
        }
    }
    #pragma unroll
    for (int nt = 0; nt < 2; nt++) {
        int n = (gnp * 2 + nt) * 16 + r;
        float bias = (n < H) ? b1[n] : 0.f;
        #pragma unroll
        for (int rr = 0; rr < 4; rr++) {
            int m = gm * 16 + 4 * q + rr;
            float C = acc[nt][rr] + bias;
            if (n < H) Up[m * H + n] = (_Float16)C;
            else       Vv[m * H + (n - H)] = (_Float16)C;
        }
    }
}

// ---------------- K2: pair MLP (448 x 128-pair tiles) + sim rides in blocks [448,464) ----------------
__global__ __launch_bounds__(256, 2) void k_pairs(const _Float16* __restrict__ Up,
                                                  const _Float16* __restrict__ Vv,
                                                  const _Float16* __restrict__ W2H,
                                                  const _Float16* __restrict__ zH,
                                                  const float* __restrict__ b2,
                                                  const float* __restrict__ W3,
                                                  const float* __restrict__ b3,
                                                  float* __restrict__ bcepart,
                                                  float* __restrict__ esp,   // [8][128]
                                                  float* __restrict__ slp) { // [8][128]
    int tid = threadIdx.x;
    int w = tid >> 6, lane = tid & 63;
    int r = lane & 15, q = lane >> 4;
    int bx = blockIdx.x;

    if (bx >= NPBLK_P) {
        // ---- similarity stats: wave tile t = (bx-448)*4+w ----
        int t = (bx - NPBLK_P) * 4 + w;      // 0..63
        int gm = t >> 3;                     // rows < 128
        int slot = t & 7;
        int gn0 = slot * 4;
        f32x4 acc[4] = {};
        #pragma unroll 4
        for (int s = 0; s < 24; s++) {
            f16x8 a = *(const f16x8*)(zH + ((gm * 24 + s) * 64 + lane) * 8);
            #pragma unroll
            for (int nt = 0; nt < 4; nt++) {
                f16x8 bb = *(const f16x8*)(zH + (((gn0 + nt) * 24 + s) * 64 + lane) * 8);
                acc[nt] = __builtin_amdgcn_mfma_f32_16x16x32_f16(a, bb, acc[nt], 0, 0, 0);
            }
        }
        #pragma unroll
        for (int rr = 0; rr < 4; rr++) {
            int irow = gm * 16 + q * 4 + rr;
            float es = 0.f, sl = 0.f;
            #pragma unroll
            for (int nt = 0; nt < 4; nt++) {
                int kcol = (gn0 + nt) * 16 + r;
                float C = acc[nt][rr];
                if (kcol != irow) es += expf(2.f * C);
                if (kcol > irow && kcol < NN) sl += 2.f * C;
            }
            #pragma unroll
            for (int m = 1; m <= 8; m <<= 1) {
                es += __shfl_xor(es, m);
                sl += __shfl_xor(sl, m);
            }
            if (r == 0) {
                esp[slot * NN + irow] = es;
                slp[slot * NN + irow] = sl;
            }
        }
        return;
    }

    // ---- pair blocks ----
    __shared__ _Float16 h1[128][264];    // 66 KB
    __shared__ float redbuf[4][128];
    __shared__ float red2[2];
    __shared__ int jrow[128];            // cached j per pair-row (R3)

    int p0 = bx * 128;

    // stage h1 = relu(U'[i] + V[j]) f16; (i,j) computed inline per unit (no barrier)
    #pragma unroll
    for (int uu = 0; uu < 2; uu++) {
        int u = uu * 256 + tid;              // 0..511
        int row = u >> 2, cq = u & 3;
        int p = p0 + row;
        if (p >= P_PAIRS) p = P_PAIRS - 1;   // pad rows duplicate last pair (masked later)
        float disc = 1046529.f - 8.f * (float)p;   // 1023^2 - 8p, exact in fp32
        int i = (int)((1023.f - sqrtf(disc)) * 0.5f);
        if (i < 0) i = 0;
        if (i > NN - 1) i = NN - 1;
        while (i > 0 && i * (1023 - i) / 2 > p) i--;
        while ((i + 1) * (1022 - i) / 2 <= p) i++;
        int j = i + 1 + (p - i * (1023 - i) / 2);
        if (cq == 0) jrow[row] = j;          // cache for BCE tail

        const _Float16* up = Up + i * H + 64 * cq;
        const _Float16* vp = Vv + j * H + 64 * cq;
        #pragma unroll
        for (int c8 = 0; c8 < 8; c8++) {
            f16x8 u8 = *(const f16x8*)(up + 8 * c8);
            f16x8 v8 = *(const f16x8*)(vp + 8 * c8);
            f16x8 zero = {};
            f16x8 hv = __builtin_elementwise_max(u8 + v8, zero);
            *(f16x8*)&h1[row][64 * cq + 8 * c8] = hv;
        }
    }
    __syncthreads();

    // MFMA: C[128 pairs][64 cols per wave] = h1 @ W2^T
    f32x4 acc[8][4] = {};                    // [mt][nt]
    #pragma unroll
    for (int s = 0; s < 8; s++) {
        f16x8 bb[4];
        #pragma unroll
        for (int nt = 0; nt < 4; nt++)
            bb[nt] = *(const f16x8*)(W2H + (((4 * w + nt) * 8 + s) * 64 + lane) * 8);
        #pragma unroll
        for (int mt = 0; mt < 8; mt++) {
            f16x8 a = *(const f16x8*)&h1[16 * mt + r][32 * s + 8 * q];
            #pragma unroll
            for (int nt = 0; nt < 4; nt++)
                acc[mt][nt] = __builtin_amdgcn_mfma_f32_16x16x32_f16(a, bb[nt], acc[mt][nt], 0, 0, 0);
        }
    }

    // epilogue: h2 = relu(C + b2), partial logit = sum_n h2*W3
    float b2v[4], w3v[4];
    #pragma unroll
    for (int nt = 0; nt < 4; nt++) {
        int n = 64 * w + 16 * nt + r;
        b2v[nt] = b2[n];
        w3v[nt] = W3[n];
    }
    #pragma unroll
    for (int mt = 0; mt < 8; mt++) {
        float part[4] = {0.f, 0.f, 0.f, 0.f};
        #pragma unroll
        for (int nt = 0; nt < 4; nt++)
            #pragma unroll
            for (int rr = 0; rr < 4; rr++) {
                float h2 = fmaxf(acc[mt][nt][rr] + b2v[nt], 0.f);
                part[rr] += h2 * w3v[nt];
            }
        #pragma unroll
        for (int rr = 0; rr < 4; rr++) {
            float v = part[rr];
            #pragma unroll
            for (int m = 1; m <= 8; m <<= 1) v += __shfl_xor(v, m);
            if (r == 0) redbuf[w][16 * mt + 4 * q + rr] = v;
        }
    }
    __syncthreads();

    if (tid < 128) {
        int p = p0 + tid;
        float lsum = 0.f;
        if (p < P_PAIRS) {
            int j = jrow[tid];               // cached during staging
            float logit = redbuf[0][tid] + redbuf[1][tid] +
                          redbuf[2][tid] + redbuf[3][tid] + b3[0];
            float label = (j < MM) ? 1.f : 0.f;
            lsum = fmaxf(logit, 0.f) - logit * label + log1pf(expf(-fabsf(logit)));
        }
        #pragma unroll
        for (int off = 32; off > 0; off >>= 1) lsum += __shfl_down(lsum, off);
        if ((tid & 63) == 0) red2[tid >> 6] = lsum;
    }
    __syncthreads();
    if (tid == 0) bcepart[bx] = red2[0] + red2[1];   // plain store, no atomic/fence
}

// ---------------- K3: final combine (single 256-tree, linearized scales) ----------------
__global__ __launch_bounds__(256) void k_final(const float* __restrict__ esp,
                                               const float* __restrict__ slp,
                                               const float* __restrict__ bcepart,
                                               float* __restrict__ out) {
    __shared__ float red[256];
    int t = threadIdx.x;
    const float scale = -2.0f * (float)(NN - 1) / (float)NN;

    // bce partials (448 entries, 2 per thread max)
    float contrib = 0.f;
    for (int p = t; p < NPBLK_P; p += 256) contrib += bcepart[p];
    contrib *= (1.0f / (float)P_PAIRS);

    // closs terms: threads [0,128) -> scale*(127-t)*log(es_t); [128,256) -> -scale*sl
    if (t < NN) {
        float es = 0.f;
        #pragma unroll
        for (int s8 = 0; s8 < 8; s8++) es += esp[s8 * NN + t];
        contrib += scale * (float)(NN - 1 - t) * logf(es);
    } else {
        int row = t - NN;
        float sl = 0.f;
        #pragma unroll
        for (int s8 = 0; s8 < 8; s8++) sl += slp[s8 * NN + row];
        contrib -= scale * sl;
    }
    red[t] = contrib;
    __syncthreads();
    #pragma unroll
    for (int st = 128; st > 0; st >>= 1) {
        if (t < st) red[t] += red[t + st];
        __syncthreads();
    }
    if (t == 0) out[0] = red[0];
}

extern "C" void kernel_launch(void* const* d_in, const int* in_sizes, int n_in,
                              void* d_out, int out_size, void* d_ws, size_t ws_size,
                              hipStream_t stream) {
    const float* emb = (const float*)d_in[0];
    const float* W1  = (const float*)d_in[1];
    const float* b1  = (const float*)d_in[2];
    const float* W2  = (const float*)d_in[3];
    const float* b2  = (const float*)d_in[4];
    const float* W3  = (const float*)d_in[5];
    const float* b3  = (const float*)d_in[6];
    float* out = (float*)d_out;

    float* ws = (float*)d_ws;
    float* esp     = ws;                         // 8*128
    float* slp     = ws + 1024;                  // 8*128
    float* bcepart = ws + 2048;                  // 448
    _Float16* zH  = (_Float16*)(ws + 3072);      // 512*768 frag-tiled
    _Float16* W1H = zH + B * D;                  // 512*768 frag-tiled
    _Float16* W2H = W1H + 2 * H * D;             // 256*256 frag-tiled
    _Float16* Up  = W2H + H * H;                 // 512*256 row-major
    _Float16* Vv  = Up + B * H;                  // 512*256 row-major

    k_prep<<<160, 256, 0, stream>>>(emb, W1, W2, zH, W1H, W2H);
    k_uv<<<256, 128, 0, stream>>>(zH, W1H, b1, Up, Vv);
    k_pairs<<<NPBLK_P + 16, 256, 0, stream>>>(Up, Vv, W2H, zH, b2, W3, b3,
                                              bcepart, esp, slp);
    k_final<<<1, 256, 0, stream>>>(esp, slp, bcepart, out);
}